// Round 6
// baseline (2172.234 us; speedup 1.0000x reference)
//
#include <hip/hip_runtime.h>
#include <hip/hip_cooperative_groups.h>

namespace cg = cooperative_groups;

// GeometryOptimalTransport: B=4, N=M=4096, C=128
// Sinkhorn (3 iters) over log_K(m,n) = -dist2/eps masked to -1e9, then
// attn-weighted gather of source feats.
//
// R2: validity is iteration-invariant -> compact neighbor lists (u16, CAP=512);
// finite NEG_INF=-1e9 contamination closed-form: empty rows give u=+1e9 exactly,
// contributing exp(0) to every column lse (per-batch count cc); all other
// invalid entries underflow to exactly 0 in fp32.
// R5: 10x10 CSR spatial bins -> ~8x fewer pair tests.
// R6: every sweep/lse variant ran ~10x above its issue floor; the common cost
// is the 13 dispatch boundaries (L2 writeback-invalidate + drain each). Fuse
// everything into ONE cooperative kernel with grid.sync() between phases.
// Block i owns rows/cols [16i,16i+16) in every phase -> its lists stay in its
// own XCD's L2 from sweep through output.

constexpr int   BB = 4;
constexpr int   NN = 4096;
constexpr int   MM = 4096;
constexpr int   CC = 128;
constexpr int   CAP = 512;                          // max neighbors (est max ~330)
constexpr int   G = 10, CSTRIDE = 104;              // 10x10 cells, padded CSR row
constexpr int   NBLK = 1024;                        // cooperative grid: 4 blocks/CU
constexpr float kNegInf    = -1000000000.0f;
constexpr float kThresh2   = 0.04f;                 // 0.2^2
constexpr float kNegInvEps = -(1.0f / 0.01000001f); // -(1/(EPSILON+1e-8))

__device__ inline float wave_reduce_max(float x) {
#pragma unroll
  for (int off = 32; off > 0; off >>= 1)
    x = fmaxf(x, __shfl_xor(x, off, 64));
  return x;
}
__device__ inline float wave_reduce_sum(float x) {
#pragma unroll
  for (int off = 32; off > 0; off >>= 1)
    x += __shfl_xor(x, off, 64);
  return x;
}
__device__ inline int lane_prefix(unsigned long long m) {
  return __builtin_amdgcn_mbcnt_hi((unsigned)(m >> 32),
         __builtin_amdgcn_mbcnt_lo((unsigned)m, 0));
}

// ---------------------------------------------------------------------------
// Phase helpers (device inline)
// ---------------------------------------------------------------------------

__device__ inline void sweep_one(
    int row, bool is_row, int lane,
    const float2* __restrict__ slm, const float2* __restrict__ tlm,
    const int* __restrict__ bin_start, const float2* __restrict__ bin_loc,
    const unsigned short* __restrict__ bin_pid,
    unsigned short* __restrict__ row_idx, int* __restrict__ row_cnt,
    unsigned short* __restrict__ col_idx, int* __restrict__ col_cnt,
    int* __restrict__ ecnt)
{
  const int b = row >> 12;
  const float2 a = (is_row ? tlm : slm)[row];
  const int sb = (is_row ? 0 : 4) + b;   // partner bins: row side -> source bins
  const int* __restrict__ bs = bin_start + (size_t)sb * CSTRIDE;
  const float2* __restrict__ bl = bin_loc + (size_t)sb * 4096;
  const unsigned short* __restrict__ bp = bin_pid + (size_t)sb * 4096;
  unsigned short* __restrict__ lst =
      (is_row ? row_idx : col_idx) + (size_t)row * CAP;

  int cnt = 0;
  if (a.x < 1.5f) {                      // real point (sentinels 1e9/3e9)
    int cx = min(max((int)(a.x * 10.0f), 0), 9);
    int cy = min(max((int)(a.y * 10.0f), 0), 9);
    int cy0 = max(cy - 2, 0), cy1 = min(cy + 2, 9);
    int cx0 = max(cx - 2, 0), cx1 = min(cx + 2, 9);
    for (int yy = cy0; yy <= cy1; ++yy) {
      int s0 = bs[yy * G + cx0];
      int s1 = bs[yy * G + cx1 + 1];
      for (int p0 = s0; p0 < s1; p0 += 64) {
        int pos = p0 + lane;
        bool act = pos < s1;
        int posc = act ? pos : p0;
        float2 s = bl[posc];
        float dx = a.x - s.x, dy = a.y - s.y;
        bool val = act && ((dx * dx + dy * dy) < kThresh2);
        unsigned long long mm = __ballot(val);
        if (val) {
          int off = cnt + lane_prefix(mm);
          if (off < CAP) lst[off] = bp[posc];
        }
        cnt += __popcll(mm);
      }
    }
    if (cnt > CAP) cnt = CAP;            // est. max ~330, never hit
  }
  if (lane == 0) {
    if (is_row) {
      row_cnt[row] = cnt;
      if (cnt == 0) atomicAdd(&ecnt[b], 1);  // includes masked target rows
    } else {
      col_cnt[row] = cnt;
    }
  }
}

__device__ inline void lse_row_one(
    int row, int lane,
    const float2* __restrict__ tlm, const float2* __restrict__ slm,
    const unsigned short* __restrict__ row_idx, const int* __restrict__ row_cnt,
    const float* __restrict__ v, float* __restrict__ u)
{
  const int cnt = row_cnt[row];
  if (cnt == 0) { if (lane == 0) u[row] = 1.0e9f; return; }
  const int b = row >> 12;
  const float2 a = tlm[row];
  const float2* __restrict__ sl = slm + (size_t)b * NN;
  const float*  __restrict__ vb = v + (size_t)b * NN;
  const unsigned short* __restrict__ lst = row_idx + (size_t)row * CAP;

  float t[CAP / 64];
  float mx = -3.0e38f;
#pragma unroll
  for (int i = 0; i < CAP / 64; ++i) {
    int j = i * 64 + lane;
    float tv = -3.0e38f;
    if (j < cnt) {
      int n = lst[j];
      float2 s = sl[n];
      float dx = a.x - s.x, dy = a.y - s.y;
      tv = (dx * dx + dy * dy) * kNegInvEps + vb[n];
    }
    t[i] = tv;
    mx = fmaxf(mx, tv);
  }
  mx = wave_reduce_max(mx);
  float ssum = 0.0f;
#pragma unroll
  for (int i = 0; i < CAP / 64; ++i) ssum += __expf(t[i] - mx);
  ssum = wave_reduce_sum(ssum);
  if (lane == 0) u[row] = -(mx + __logf(ssum));
}

__device__ inline void lse_col_one(
    int col, int lane,
    const float2* __restrict__ slm, const float2* __restrict__ tlm,
    const unsigned short* __restrict__ col_idx, const int* __restrict__ col_cnt,
    const int* __restrict__ smask, const int* __restrict__ ecnt,
    const float* __restrict__ u, float* __restrict__ v)
{
  if (!smask[col]) { if (lane == 0) v[col] = 0.0f; return; }
  const int cnt = col_cnt[col];
  const int b   = col >> 12;
  const int cc  = ecnt[b];
  if (cnt == 0 && cc == 0) { if (lane == 0) v[col] = 1.0e9f; return; }
  const float2 a = slm[col];
  const float2* __restrict__ tl = tlm + (size_t)b * MM;
  const float*  __restrict__ ub = u + (size_t)b * MM;
  const unsigned short* __restrict__ lst = col_idx + (size_t)col * CAP;

  float t[CAP / 64];
  float mx = -3.0e38f;
#pragma unroll
  for (int i = 0; i < CAP / 64; ++i) {
    int j = i * 64 + lane;
    float tv = -3.0e38f;
    if (j < cnt) {
      int m = lst[j];
      float2 s = tl[m];
      float dx = a.x - s.x, dy = a.y - s.y;
      tv = (dx * dx + dy * dy) * kNegInvEps + ub[m];
    }
    t[i] = tv;
    mx = fmaxf(mx, tv);
  }
  mx = wave_reduce_max(mx);
  if (cc > 0) mx = fmaxf(mx, 0.0f);   // contamination entries are t = 0.0 exactly
  float ssum = 0.0f;
#pragma unroll
  for (int i = 0; i < CAP / 64; ++i) ssum += __expf(t[i] - mx);
  ssum = wave_reduce_sum(ssum);
  if (lane == 0) v[col] = -(mx + __logf(ssum + (float)cc * __expf(0.0f - mx)));
}

__device__ inline void output_one(
    int row, int tid,
    const float2* __restrict__ tlm, const float2* __restrict__ slm,
    const unsigned short* __restrict__ row_idx, const int* __restrict__ row_cnt,
    const float* __restrict__ u, const float* __restrict__ v,
    const float* __restrict__ feats, float* __restrict__ out,
    float* s_attn, unsigned short* s_id, float4* s_red)
{
  const int b = row >> 12;
  const int cnt = row_cnt[row];            // block-uniform
  float4* op = (float4*)(out + (size_t)row * CC);
  if (cnt == 0) {                          // covers !tgt_valid and !has_source
    if (tid < 32) op[tid] = make_float4(0.f, 0.f, 0.f, 0.f);
    return;
  }
  const float um = u[row];
  const float2 a = tlm[row];
  const float2* __restrict__ sl = slm + (size_t)b * NN;
  const float*  __restrict__ vb = v + (size_t)b * NN;
  const unsigned short* __restrict__ lst = row_idx + (size_t)row * CAP;

  for (int j = tid; j < cnt; j += 256) {
    int n = lst[j];
    float2 s = sl[n];
    float dx = a.x - s.x, dy = a.y - s.y;
    s_attn[j] = __expf((dx * dx + dy * dy) * kNegInvEps + um + vb[n]);
    s_id[j] = (unsigned short)n;
  }
  __syncthreads();

  const int g = tid >> 5, l = tid & 31;
  const float4* __restrict__ fb = (const float4*)(feats + (size_t)b * NN * CC);
  float4 acc = make_float4(0.f, 0.f, 0.f, 0.f);
  for (int j = g; j < cnt; j += 8) {
    float aw = s_attn[j];
    int   n  = s_id[j];
    float4 f = fb[(size_t)n * 32 + l];
    acc.x = fmaf(aw, f.x, acc.x);
    acc.y = fmaf(aw, f.y, acc.y);
    acc.z = fmaf(aw, f.z, acc.z);
    acc.w = fmaf(aw, f.w, acc.w);
  }
  s_red[tid] = acc;
  __syncthreads();
  if (tid < 32) {
    float4 r = s_red[tid];
#pragma unroll
    for (int gg = 1; gg < 8; ++gg) {
      float4 p = s_red[gg * 32 + tid];
      r.x += p.x; r.y += p.y; r.z += p.z; r.w += p.w;
    }
    op[tid] = r;
  }
  __syncthreads();                        // protect LDS reuse by next row
}

// ---------------------------------------------------------------------------
// The fused cooperative kernel
// ---------------------------------------------------------------------------

__global__ __launch_bounds__(256, 4) void fused_kernel(
    const float* __restrict__ feats,
    const float* __restrict__ sloc, const float* __restrict__ tloc,
    const int* __restrict__ smask, const int* __restrict__ tmask,
    float* __restrict__ out,
    float* __restrict__ u, float* __restrict__ v,
    int* __restrict__ row_cnt, int* __restrict__ col_cnt, int* __restrict__ ecnt,
    float2* __restrict__ slm, float2* __restrict__ tlm,
    unsigned short* __restrict__ row_idx, unsigned short* __restrict__ col_idx,
    int* __restrict__ bin_start, float2* __restrict__ bin_loc,
    unsigned short* __restrict__ bin_pid)
{
  cg::grid_group grid = cg::this_grid();
  const int tid  = threadIdx.x;
  const int wid  = tid >> 6;
  const int lane = tid & 63;
  const int blk  = blockIdx.x;

  __shared__ int s_cnt[128];
  __shared__ int s_base[128];
  __shared__ float s_attn[CAP];
  __shared__ unsigned short s_id[CAP];
  __shared__ float4 s_red[256];

  // ---- phase 0: prep (mask-fold, zero v/ecnt) + bins (blocks 0..7) ----
  {
    int i = blk * 256 + tid;
    if (i < BB * NN) {
      v[i] = 0.0f;
      float2 s = ((const float2*)sloc)[i];
      slm[i] = smask[i] ? s : make_float2(1.0e9f, 1.0e9f);
      float2 t = ((const float2*)tloc)[i];
      tlm[i] = tmask[i] ? t : make_float2(3.0e9f, 3.0e9f);
      if (i < BB) ecnt[i] = 0;
    }
  }
  if (blk < 8) {
    const int side = blk >> 2;             // 0 = sources, 1 = targets
    const int b    = blk & 3;
    const float2* __restrict__ loc =
        (const float2*)(side == 0 ? sloc : tloc) + (size_t)b * 4096;
    const int* __restrict__ msk = (side == 0 ? smask : tmask) + (size_t)b * 4096;
    int* __restrict__ bsw = bin_start + (size_t)blk * CSTRIDE;
    float2* __restrict__ bloc = bin_loc + (size_t)blk * 4096;
    unsigned short* __restrict__ bpid = bin_pid + (size_t)blk * 4096;

    if (tid < 128) s_cnt[tid] = 0;
    __syncthreads();
    for (int i = tid; i < 4096; i += 256) {
      if (msk[i]) {
        float2 p = loc[i];
        int cx = min(max((int)(p.x * 10.0f), 0), 9);
        int cy = min(max((int)(p.y * 10.0f), 0), 9);
        atomicAdd(&s_cnt[cy * G + cx], 1);
      }
    }
    __syncthreads();
    if (tid < 64) {
      int x0 = s_cnt[tid], x1 = s_cnt[64 + tid];
      int s0 = x0;
#pragma unroll
      for (int off = 1; off < 64; off <<= 1) {
        int y = __shfl_up(s0, off, 64);
        if (tid >= off) s0 += y;
      }
      int tot0 = __shfl(s0, 63, 64);
      int s1 = x1;
#pragma unroll
      for (int off = 1; off < 64; off <<= 1) {
        int y = __shfl_up(s1, off, 64);
        if (tid >= off) s1 += y;
      }
      s1 += tot0;
      s_base[tid] = s0 - x0;
      s_base[64 + tid] = s1 - x1;
      bsw[tid] = s0 - x0;
      if (64 + tid < CSTRIDE) bsw[64 + tid] = s1 - x1;
    }
    __syncthreads();
    for (int i = tid; i < 4096; i += 256) {
      if (msk[i]) {
        float2 p = loc[i];
        int cx = min(max((int)(p.x * 10.0f), 0), 9);
        int cy = min(max((int)(p.y * 10.0f), 0), 9);
        int pos = atomicAdd(&s_base[cy * G + cx], 1);
        bloc[pos] = p;
        bpid[pos] = (unsigned short)i;
      }
    }
  }
  __threadfence();
  grid.sync();

  // ---- phase 1: sweep (block owns rows/cols [16*blk, 16*blk+16)) ----
#pragma unroll
  for (int k = 0; k < 4; ++k)
    sweep_one(blk * 16 + wid * 4 + k, true, lane, slm, tlm,
              bin_start, bin_loc, bin_pid,
              row_idx, row_cnt, col_idx, col_cnt, ecnt);
#pragma unroll
  for (int k = 0; k < 4; ++k)
    sweep_one(blk * 16 + wid * 4 + k, false, lane, slm, tlm,
              bin_start, bin_loc, bin_pid,
              row_idx, row_cnt, col_idx, col_cnt, ecnt);
  __threadfence();
  grid.sync();

  // ---- phases 2-7: 3 x (u-update, v-update) ----
  for (int it = 0; it < 3; ++it) {
#pragma unroll
    for (int k = 0; k < 4; ++k)
      lse_row_one(blk * 16 + wid * 4 + k, lane, tlm, slm,
                  row_idx, row_cnt, v, u);
    __threadfence();
    grid.sync();
#pragma unroll
    for (int k = 0; k < 4; ++k)
      lse_col_one(blk * 16 + wid * 4 + k, lane, slm, tlm,
                  col_idx, col_cnt, smask, ecnt, u, v);
    __threadfence();
    grid.sync();
  }

  // ---- phase 8: output (block loops over its 16 rows) ----
  for (int k = 0; k < 16; ++k)
    output_one(blk * 16 + k, tid, tlm, slm, row_idx, row_cnt,
               u, v, feats, out, s_attn, s_id, s_red);
}

// ---------------------------------------------------------------------------
// FALLBACK A: R5 multi-kernel path (output swizzle reverted)
// ---------------------------------------------------------------------------

__global__ __launch_bounds__(256) void prep_kernel(
    const float* __restrict__ sloc, const float* __restrict__ tloc,
    const int* __restrict__ sm, const int* __restrict__ tm,
    float* __restrict__ v, int* __restrict__ ecnt,
    float2* __restrict__ slm, float2* __restrict__ tlm)
{
  int i = blockIdx.x * 256 + threadIdx.x;
  if (i < BB * NN) {
    v[i] = 0.0f;
    float2 s = ((const float2*)sloc)[i];
    slm[i] = sm[i] ? s : make_float2(1.0e9f, 1.0e9f);
    float2 t = ((const float2*)tloc)[i];
    tlm[i] = tm[i] ? t : make_float2(3.0e9f, 3.0e9f);
    if (i < BB) ecnt[i] = 0;
  }
}

__global__ __launch_bounds__(256) void build_bins_kernel(
    const float* __restrict__ sloc, const float* __restrict__ tloc,
    const int* __restrict__ sm, const int* __restrict__ tm,
    int* __restrict__ bin_start, float2* __restrict__ bin_loc,
    unsigned short* __restrict__ bin_pid)
{
  __shared__ int s_cnt[128];
  __shared__ int s_base[128];
  const int side = blockIdx.x >> 2;
  const int b    = blockIdx.x & 3;
  const int tid  = threadIdx.x;
  const float2* __restrict__ loc =
      (const float2*)(side == 0 ? sloc : tloc) + (size_t)b * 4096;
  const int* __restrict__ msk = (side == 0 ? sm : tm) + (size_t)b * 4096;
  int* __restrict__ bs = bin_start + (size_t)blockIdx.x * CSTRIDE;
  float2* __restrict__ bloc = bin_loc + (size_t)blockIdx.x * 4096;
  unsigned short* __restrict__ bpid = bin_pid + (size_t)blockIdx.x * 4096;

  if (tid < 128) s_cnt[tid] = 0;
  __syncthreads();
  for (int i = tid; i < 4096; i += 256) {
    if (msk[i]) {
      float2 p = loc[i];
      int cx = min(max((int)(p.x * 10.0f), 0), 9);
      int cy = min(max((int)(p.y * 10.0f), 0), 9);
      atomicAdd(&s_cnt[cy * G + cx], 1);
    }
  }
  __syncthreads();
  if (tid < 64) {
    int x0 = s_cnt[tid], x1 = s_cnt[64 + tid];
    int s0 = x0;
#pragma unroll
    for (int off = 1; off < 64; off <<= 1) {
      int y = __shfl_up(s0, off, 64);
      if (tid >= off) s0 += y;
    }
    int tot0 = __shfl(s0, 63, 64);
    int s1 = x1;
#pragma unroll
    for (int off = 1; off < 64; off <<= 1) {
      int y = __shfl_up(s1, off, 64);
      if (tid >= off) s1 += y;
    }
    s1 += tot0;
    s_base[tid] = s0 - x0;
    s_base[64 + tid] = s1 - x1;
    bs[tid] = s0 - x0;
    if (64 + tid < CSTRIDE) bs[64 + tid] = s1 - x1;
  }
  __syncthreads();
  for (int i = tid; i < 4096; i += 256) {
    if (msk[i]) {
      float2 p = loc[i];
      int cx = min(max((int)(p.x * 10.0f), 0), 9);
      int cy = min(max((int)(p.y * 10.0f), 0), 9);
      int pos = atomicAdd(&s_base[cy * G + cx], 1);
      bloc[pos] = p;
      bpid[pos] = (unsigned short)i;
    }
  }
}

__global__ __launch_bounds__(256) void sweep4_kernel(
    const float2* __restrict__ slm, const float2* __restrict__ tlm,
    const int* __restrict__ bin_start, const float2* __restrict__ bin_loc,
    const unsigned short* __restrict__ bin_pid,
    unsigned short* __restrict__ row_idx, int* __restrict__ row_cnt,
    unsigned short* __restrict__ col_idx, int* __restrict__ col_cnt,
    int* __restrict__ ecnt)
{
  const bool is_row = blockIdx.x < (BB * MM / 4);
  const int  rbase  = (is_row ? blockIdx.x : blockIdx.x - BB * MM / 4) * 4;
  const int  lane   = threadIdx.x & 63;
  const int  row    = rbase + (threadIdx.x >> 6);
  sweep_one(row, is_row, lane, slm, tlm, bin_start, bin_loc, bin_pid,
            row_idx, row_cnt, col_idx, col_cnt, ecnt);
}

__global__ __launch_bounds__(256) void lse_row_kernel(
    const float2* __restrict__ tlm, const float2* __restrict__ slm,
    const unsigned short* __restrict__ row_idx, const int* __restrict__ row_cnt,
    const float* __restrict__ v, float* __restrict__ u)
{
  const int lane = threadIdx.x & 63;
  const int row  = blockIdx.x * 4 + (threadIdx.x >> 6);
  lse_row_one(row, lane, tlm, slm, row_idx, row_cnt, v, u);
}

__global__ __launch_bounds__(256) void lse_col_kernel(
    const float2* __restrict__ slm, const float2* __restrict__ tlm,
    const unsigned short* __restrict__ col_idx, const int* __restrict__ col_cnt,
    const int* __restrict__ smask, const int* __restrict__ ecnt,
    const float* __restrict__ u, float* __restrict__ v)
{
  const int lane = threadIdx.x & 63;
  const int col  = blockIdx.x * 4 + (threadIdx.x >> 6);
  lse_col_one(col, lane, slm, tlm, col_idx, col_cnt, smask, ecnt, u, v);
}

__global__ __launch_bounds__(256) void output2_kernel(
    const float2* __restrict__ tlm, const float2* __restrict__ slm,
    const unsigned short* __restrict__ row_idx, const int* __restrict__ row_cnt,
    const float* __restrict__ u, const float* __restrict__ v,
    const float* __restrict__ feats, float* __restrict__ out)
{
  __shared__ float s_attn[CAP];
  __shared__ unsigned short s_id[CAP];
  __shared__ float4 s_red[256];
  output_one(blockIdx.x, threadIdx.x, tlm, slm, row_idx, row_cnt,
             u, v, feats, out, s_attn, s_id, s_red);
}

// ---------------------------------------------------------------------------
// FALLBACK B: round-1 dense path (~128 KB workspace)
// ---------------------------------------------------------------------------

__global__ __launch_bounds__(256) void init_v_kernel(float* __restrict__ v) {
  int i = blockIdx.x * 256 + threadIdx.x;
  if (i < BB * NN) v[i] = 0.0f;
}

__global__ __launch_bounds__(256) void u_update_kernel(
    const float* __restrict__ src_locs, const float* __restrict__ tgt_locs,
    const int* __restrict__ src_valid, const int* __restrict__ tgt_valid,
    const float* __restrict__ v, float* __restrict__ u)
{
  const int lane = threadIdx.x & 63;
  const int row  = blockIdx.x * 4 + (threadIdx.x >> 6);
  const int b    = row / MM;
  const float tx = tgt_locs[row * 2 + 0];
  const float ty = tgt_locs[row * 2 + 1];
  const bool  tv = tgt_valid[row] != 0;
  const float2* __restrict__ sl  = (const float2*)(src_locs + (size_t)b * NN * 2);
  const float*  __restrict__ vb  = v + (size_t)b * NN;
  const int*    __restrict__ svb = src_valid + (size_t)b * NN;
  float mx = -3.0e38f;
#pragma unroll 4
  for (int i = 0; i < NN / 64; ++i) {
    int n = i * 64 + lane;
    float2 s = sl[n];
    float dx = tx - s.x, dy = ty - s.y;
    float d2 = dx * dx + dy * dy;
    bool valid = (d2 < kThresh2) & tv & (svb[n] != 0);
    float t = (valid ? d2 * kNegInvEps : kNegInf) + vb[n];
    mx = fmaxf(mx, t);
  }
  mx = wave_reduce_max(mx);
  float s = 0.0f;
#pragma unroll 4
  for (int i = 0; i < NN / 64; ++i) {
    int n = i * 64 + lane;
    float2 sc = sl[n];
    float dx = tx - sc.x, dy = ty - sc.y;
    float d2 = dx * dx + dy * dy;
    bool valid = (d2 < kThresh2) & tv & (svb[n] != 0);
    float t = (valid ? d2 * kNegInvEps : kNegInf) + vb[n];
    s += __expf(t - mx);
  }
  s = wave_reduce_sum(s);
  if (lane == 0) u[row] = -(mx + __logf(s));
}

__global__ __launch_bounds__(256) void v_update_kernel(
    const float* __restrict__ src_locs, const float* __restrict__ tgt_locs,
    const int* __restrict__ src_valid, const int* __restrict__ tgt_valid,
    const float* __restrict__ u, float* __restrict__ v)
{
  const int lane = threadIdx.x & 63;
  const int col  = blockIdx.x * 4 + (threadIdx.x >> 6);
  const int b    = col / NN;
  const float sx = src_locs[col * 2 + 0];
  const float sy = src_locs[col * 2 + 1];
  const bool  sv = src_valid[col] != 0;
  const float2* __restrict__ tl  = (const float2*)(tgt_locs + (size_t)b * MM * 2);
  const float*  __restrict__ ub  = u + (size_t)b * MM;
  const int*    __restrict__ tvb = tgt_valid + (size_t)b * MM;
  float mx = -3.0e38f;
#pragma unroll 4
  for (int i = 0; i < MM / 64; ++i) {
    int m = i * 64 + lane;
    float2 t2 = tl[m];
    float dx = t2.x - sx, dy = t2.y - sy;
    float d2 = dx * dx + dy * dy;
    bool valid = (d2 < kThresh2) & sv & (tvb[m] != 0);
    float t = (valid ? d2 * kNegInvEps : kNegInf) + ub[m];
    mx = fmaxf(mx, t);
  }
  mx = wave_reduce_max(mx);
  float s = 0.0f;
#pragma unroll 4
  for (int i = 0; i < MM / 64; ++i) {
    int m = i * 64 + lane;
    float2 t2 = tl[m];
    float dx = t2.x - sx, dy = t2.y - sy;
    float d2 = dx * dx + dy * dy;
    bool valid = (d2 < kThresh2) & sv & (tvb[m] != 0);
    float t = (valid ? d2 * kNegInvEps : kNegInf) + ub[m];
    s += __expf(t - mx);
  }
  s = wave_reduce_sum(s);
  if (lane == 0) v[col] = sv ? -(mx + __logf(s)) : 0.0f;
}

__global__ __launch_bounds__(256) void output_kernel(
    const float* __restrict__ src_locs, const float* __restrict__ tgt_locs,
    const int* __restrict__ src_valid, const int* __restrict__ tgt_valid,
    const float* __restrict__ u, const float* __restrict__ v,
    const float* __restrict__ feats, float* __restrict__ out)
{
  __shared__ float s_attn[NN];
  __shared__ int   s_idx[NN];
  __shared__ int   s_cnt;
  __shared__ float s_part[CC];
  const int row = blockIdx.x;
  const int b   = row / MM;
  const int tid = threadIdx.x;
  if (tid == 0) s_cnt = 0;
  __syncthreads();
  const float tx = tgt_locs[row * 2 + 0];
  const float ty = tgt_locs[row * 2 + 1];
  const bool  tv = tgt_valid[row] != 0;
  const float um = u[row];
  const float2* __restrict__ sl  = (const float2*)(src_locs + (size_t)b * NN * 2);
  const float*  __restrict__ vb  = v + (size_t)b * NN;
  const int*    __restrict__ svb = src_valid + (size_t)b * NN;
#pragma unroll 4
  for (int i = 0; i < NN / 256; ++i) {
    int n = i * 256 + tid;
    float2 s = sl[n];
    float dx = tx - s.x, dy = ty - s.y;
    float d2 = dx * dx + dy * dy;
    bool valid = (d2 < kThresh2) & tv & (svb[n] != 0);
    if (valid) {
      float a = __expf((d2 * kNegInvEps + um) + vb[n]);
      int p = atomicAdd(&s_cnt, 1);
      s_attn[p] = a;
      s_idx[p]  = n;
    }
  }
  __syncthreads();
  const int cnt = s_cnt;
  const int g = tid >> 7;
  const int c = tid & (CC - 1);
  const float* __restrict__ fb = feats + (size_t)b * NN * CC;
  float acc = 0.0f;
  for (int j = g; j < cnt; j += 2) {
    float a = s_attn[j];
    int   n = s_idx[j];
    acc = fmaf(a, fb[(size_t)n * CC + c], acc);
  }
  if (g == 1) s_part[c] = acc;
  __syncthreads();
  if (g == 0) {
    float r = (cnt > 0) ? (acc + s_part[c]) : 0.0f;
    out[(size_t)row * CC + c] = r;
  }
}

// ---------------------------------------------------------------------------

extern "C" void kernel_launch(void* const* d_in, const int* in_sizes, int n_in,
                              void* d_out, int out_size, void* d_ws, size_t ws_size,
                              hipStream_t stream) {
  const float* feats = (const float*)d_in[0];
  const float* sloc  = (const float*)d_in[1];
  const float* tloc  = (const float*)d_in[2];
  const int*   smask = (const int*)d_in[3];
  const int*   tmask = (const int*)d_in[4];
  float* out = (float*)d_out;

  // workspace layout
  char* p = (char*)d_ws;
  float* u_   = (float*)p;            p += (size_t)BB * MM * 4;
  float* v_   = (float*)p;            p += (size_t)BB * NN * 4;
  int* row_cnt = (int*)p;             p += (size_t)BB * MM * 4;
  int* col_cnt = (int*)p;             p += (size_t)BB * NN * 4;
  int* ecnt    = (int*)p;             p += 256;
  float2* slm  = (float2*)p;          p += (size_t)BB * NN * 8;
  float2* tlm  = (float2*)p;          p += (size_t)BB * MM * 8;
  unsigned short* row_idx = (unsigned short*)p; p += (size_t)BB * MM * CAP * 2;
  unsigned short* col_idx = (unsigned short*)p; p += (size_t)BB * NN * CAP * 2;
  int* bin_start = (int*)p;           p += (size_t)8 * CSTRIDE * 4;
  float2* bin_loc = (float2*)p;       p += (size_t)8 * 4096 * 8;
  unsigned short* bin_pid = (unsigned short*)p; p += (size_t)8 * 4096 * 2;
  size_t required = (size_t)(p - (char*)d_ws);

  if (ws_size >= required) {
    void* args[] = {
      (void*)&feats, (void*)&sloc, (void*)&tloc, (void*)&smask, (void*)&tmask,
      (void*)&out, (void*)&u_, (void*)&v_, (void*)&row_cnt, (void*)&col_cnt,
      (void*)&ecnt, (void*)&slm, (void*)&tlm, (void*)&row_idx, (void*)&col_idx,
      (void*)&bin_start, (void*)&bin_loc, (void*)&bin_pid
    };
    hipError_t err = hipLaunchCooperativeKernel(
        (const void*)fused_kernel, dim3(NBLK), dim3(256), args, 0, stream);
    if (err == hipSuccess) return;

    // cooperative launch unavailable -> R5 multi-kernel path
    prep_kernel<<<(BB * NN + 255) / 256, 256, 0, stream>>>(
        sloc, tloc, smask, tmask, v_, ecnt, slm, tlm);
    build_bins_kernel<<<8, 256, 0, stream>>>(
        sloc, tloc, smask, tmask, bin_start, bin_loc, bin_pid);
    sweep4_kernel<<<2 * BB * MM / 4, 256, 0, stream>>>(
        slm, tlm, bin_start, bin_loc, bin_pid,
        row_idx, row_cnt, col_idx, col_cnt, ecnt);
    for (int it = 0; it < 3; ++it) {
      lse_row_kernel<<<BB * MM / 4, 256, 0, stream>>>(tlm, slm, row_idx, row_cnt, v_, u_);
      lse_col_kernel<<<BB * NN / 4, 256, 0, stream>>>(slm, tlm, col_idx, col_cnt,
                                                      smask, ecnt, u_, v_);
    }
    output2_kernel<<<BB * MM, 256, 0, stream>>>(tlm, slm, row_idx, row_cnt,
                                                u_, v_, feats, out);
  } else {
    // minimal-workspace fallback: round-1 dense path
    float* u = (float*)d_ws;
    float* v = u + (size_t)BB * MM;
    init_v_kernel<<<(BB * NN + 255) / 256, 256, 0, stream>>>(v);
    for (int it = 0; it < 3; ++it) {
      u_update_kernel<<<BB * MM / 4, 256, 0, stream>>>(sloc, tloc, smask, tmask, v, u);
      v_update_kernel<<<BB * NN / 4, 256, 0, stream>>>(sloc, tloc, smask, tmask, u, v);
    }
    output_kernel<<<BB * MM, 256, 0, stream>>>(sloc, tloc, smask, tmask, u, v, feats, out);
  }
}

// Round 7
// 302.284 us; speedup vs baseline: 7.1861x; 7.1861x over previous
//
#include <hip/hip_runtime.h>

// GeometryOptimalTransport: B=4, N=M=4096, C=128
// Sinkhorn (3 iters) over log_K(m,n) = -dist2/eps masked to -1e9, then
// attn-weighted gather of source feats.
//
// R2: validity is iteration-invariant -> compact neighbor lists (u16, CAP=512);
// finite NEG_INF=-1e9 contamination closed-form: empty rows give u=+1e9 exactly,
// contributing exp(0) to every column lse (per-batch count cc); all other
// invalid entries underflow to exactly 0 in fp32.
// R5: 10x10 CSR spatial bins -> ~8x fewer pair tests.
// R6: cooperative-fusion FAILED (grid.sync flushes caches device-wide, 7x
// regression). Multi-kernel restored, no output swizzle.
// R7: sweep duration was invariant to work (108-134us) because every variant
// kept a serial load->ballot->store chain (each ballot forces a waitcnt on the
// just-issued load). sweep5 issues ALL candidate loads independently up front
// (12 slots x (8B loc + 2B pid)), then does a pure-VALU ballot/store epilogue.
// prep+bins fused into one dispatch; output2 gather loop unrolled x4 for MLP.

constexpr int   BB = 4;
constexpr int   NN = 4096;
constexpr int   MM = 4096;
constexpr int   CC = 128;
constexpr int   CAP = 512;                          // max final neighbors (est max ~330)
constexpr int   NSLOT = 12;                         // 768 candidate slots (+11 sigma)
constexpr int   G = 10, CSTRIDE = 104;              // 10x10 cells, padded CSR row
constexpr float kNegInf    = -1000000000.0f;
constexpr float kThresh2   = 0.04f;                 // 0.2^2
constexpr float kNegInvEps = -(1.0f / 0.01000001f); // -(1/(EPSILON+1e-8))

__device__ inline float wave_reduce_max(float x) {
#pragma unroll
  for (int off = 32; off > 0; off >>= 1)
    x = fmaxf(x, __shfl_xor(x, off, 64));
  return x;
}
__device__ inline float wave_reduce_sum(float x) {
#pragma unroll
  for (int off = 32; off > 0; off >>= 1)
    x += __shfl_xor(x, off, 64);
  return x;
}
__device__ inline int lane_prefix(unsigned long long m) {
  return __builtin_amdgcn_mbcnt_hi((unsigned)(m >> 32),
         __builtin_amdgcn_mbcnt_lo((unsigned)m, 0));
}

// ---------------------------------------------------------------------------
// FAST PATH (needs ~35 MB workspace)
// ---------------------------------------------------------------------------

// Fused prep (mask-fold locs, zero v/ecnt; blocks 0..63) + bin build
// (blocks 64..71: side = (blk-64)>>2, batch = (blk-64)&3).
__global__ __launch_bounds__(256) void prep_bins_kernel(
    const float* __restrict__ sloc, const float* __restrict__ tloc,
    const int* __restrict__ sm, const int* __restrict__ tm,
    float* __restrict__ v, int* __restrict__ ecnt,
    float2* __restrict__ slm, float2* __restrict__ tlm,
    int* __restrict__ bin_start, float2* __restrict__ bin_loc,
    unsigned short* __restrict__ bin_pid)
{
  __shared__ int s_cnt[128];
  __shared__ int s_base[128];
  const int blk = blockIdx.x;
  const int tid = threadIdx.x;

  if (blk < 64) {
    // prep: invalid -> far sentinel (different per side so two invalid
    // points are never "close")
    int i = blk * 256 + tid;            // always < 16384
    v[i] = 0.0f;
    float2 s = ((const float2*)sloc)[i];
    slm[i] = sm[i] ? s : make_float2(1.0e9f, 1.0e9f);
    float2 t = ((const float2*)tloc)[i];
    tlm[i] = tm[i] ? t : make_float2(3.0e9f, 3.0e9f);
    if (i < BB) ecnt[i] = 0;
    return;
  }

  // bins: LDS count -> wave prefix scan -> atomic scatter (valid points only)
  const int bb   = blk - 64;
  const int side = bb >> 2;              // 0 = sources, 1 = targets
  const int b    = bb & 3;
  const float2* __restrict__ loc =
      (const float2*)(side == 0 ? sloc : tloc) + (size_t)b * 4096;
  const int* __restrict__ msk = (side == 0 ? sm : tm) + (size_t)b * 4096;
  int* __restrict__ bsw = bin_start + (size_t)bb * CSTRIDE;
  float2* __restrict__ bloc = bin_loc + (size_t)bb * 4096;
  unsigned short* __restrict__ bpid = bin_pid + (size_t)bb * 4096;

  if (tid < 128) s_cnt[tid] = 0;
  __syncthreads();
  for (int i = tid; i < 4096; i += 256) {
    if (msk[i]) {
      float2 p = loc[i];
      int cx = min(max((int)(p.x * 10.0f), 0), 9);
      int cy = min(max((int)(p.y * 10.0f), 0), 9);
      atomicAdd(&s_cnt[cy * G + cx], 1);
    }
  }
  __syncthreads();
  if (tid < 64) {
    int x0 = s_cnt[tid], x1 = s_cnt[64 + tid];
    int s0 = x0;
#pragma unroll
    for (int off = 1; off < 64; off <<= 1) {
      int y = __shfl_up(s0, off, 64);
      if (tid >= off) s0 += y;
    }
    int tot0 = __shfl(s0, 63, 64);
    int s1 = x1;
#pragma unroll
    for (int off = 1; off < 64; off <<= 1) {
      int y = __shfl_up(s1, off, 64);
      if (tid >= off) s1 += y;
    }
    s1 += tot0;
    s_base[tid] = s0 - x0;               // exclusive starts, cells 0..63
    s_base[64 + tid] = s1 - x1;          // cells 64..127 (cells >=100 = total)
    bsw[tid] = s0 - x0;
    if (64 + tid < CSTRIDE) bsw[64 + tid] = s1 - x1;
  }
  __syncthreads();
  for (int i = tid; i < 4096; i += 256) {
    if (msk[i]) {
      float2 p = loc[i];
      int cx = min(max((int)(p.x * 10.0f), 0), 9);
      int cy = min(max((int)(p.y * 10.0f), 0), 9);
      int pos = atomicAdd(&s_base[cy * G + cx], 1);
      bloc[pos] = p;
      bpid[pos] = (unsigned short)i;
    }
  }
}

// Binned sweep, load-all-then-compact. Blocks [0,4096): row side (targets vs
// source bins); [4096,8192): col side. One wave per row. The 5x5 cell window
// collapses to 5 CSR segments; 12 fixed slots map q=64j+lane -> segment via
// cndmask chain. ALL 24 loads are independent (issued before any ballot).
__global__ __launch_bounds__(256) void sweep5_kernel(
    const float2* __restrict__ slm, const float2* __restrict__ tlm,
    const int* __restrict__ bin_start, const float2* __restrict__ bin_loc,
    const unsigned short* __restrict__ bin_pid,
    unsigned short* __restrict__ row_idx, int* __restrict__ row_cnt,
    unsigned short* __restrict__ col_idx, int* __restrict__ col_cnt,
    int* __restrict__ ecnt)
{
  const bool is_row = blockIdx.x < (BB * MM / 4);
  const int  rbase  = (is_row ? blockIdx.x : blockIdx.x - BB * MM / 4) * 4;
  const int  b      = rbase >> 12;
  const int  lane   = threadIdx.x & 63;
  const int  row    = rbase + (threadIdx.x >> 6);

  const float2 a = (is_row ? tlm : slm)[row];
  const int sb = (is_row ? 0 : 4) + b;   // row side reads source bins
  const int* __restrict__ bs = bin_start + (size_t)sb * CSTRIDE;
  const float2* __restrict__ bl = bin_loc + (size_t)sb * 4096;
  const unsigned short* __restrict__ bp = bin_pid + (size_t)sb * 4096;
  unsigned short* __restrict__ lst =
      (is_row ? row_idx : col_idx) + (size_t)row * CAP;

  int cnt = 0;
  if (a.x < 1.5f) {                      // real point (sentinels 1e9/3e9)
    int cx = min(max((int)(a.x * 10.0f), 0), 9);
    int cy = min(max((int)(a.y * 10.0f), 0), 9);
    int cy0 = max(cy - 2, 0), cy1 = min(cy + 2, 9);
    int cx0 = max(cx - 2, 0), cx1 = min(cx + 2, 9);
    const int nseg = cy1 - cy0 + 1;

    // segment table (<=5 segments, contiguous CSR ranges)
    int s0[5], Lc[6];
    Lc[0] = 0;
#pragma unroll
    for (int k = 0; k < 5; ++k) {
      int yy = min(cy0 + k, 9);          // clamp keeps bs index in range
      bool act = k < nseg;
      int i0 = bs[yy * G + cx0];
      int i1 = bs[yy * G + cx1 + 1];
      s0[k] = i0;
      Lc[k + 1] = Lc[k] + (act ? (i1 - i0) : 0);
    }
    int T = Lc[5];
    if (T > NSLOT * 64) T = NSLOT * 64;  // +11 sigma, effectively never

    // phase 1: all candidate loads, fully independent
    float d2s[NSLOT];
    int   pids[NSLOT];
#pragma unroll
    for (int j = 0; j < NSLOT; ++j) {
      int q = j * 64 + lane;
      int adj = s0[0];                   // pos = q + (s0[k] - Lc[k]) for seg k
#pragma unroll
      for (int k = 1; k < 5; ++k)
        adj = (q >= Lc[k]) ? (s0[k] - Lc[k]) : adj;
      bool act = q < T;
      int posc = act ? (q + adj) : 0;    // pos < total <= 4096 when act
      float2 s = bl[posc];
      int pid = bp[posc];
      float dx = a.x - s.x, dy = a.y - s.y;
      d2s[j] = act ? (dx * dx + dy * dy) : 1.0e9f;
      pids[j] = pid;
    }

    // phase 2: ballot/compact epilogue (pure VALU, loads already retired)
#pragma unroll
    for (int j = 0; j < NSLOT; ++j) {
      bool val = d2s[j] < kThresh2;
      unsigned long long mm = __ballot(val);
      if (val) {
        int off = cnt + lane_prefix(mm);
        if (off < CAP) lst[off] = (unsigned short)pids[j];
      }
      cnt += __popcll(mm);
    }
    if (cnt > CAP) cnt = CAP;            // est. max ~330, never hit
  }
  if (lane == 0) {
    if (is_row) {
      row_cnt[row] = cnt;
      if (cnt == 0) atomicAdd(&ecnt[b], 1);  // includes masked target rows
    } else {
      col_cnt[row] = cnt;
    }
  }
}

// u[row] = cnt ? -lse_j(logK_j + v[n_j]) : +1e9  (one wave per row)
__global__ __launch_bounds__(256) void lse_row_kernel(
    const float2* __restrict__ tlm, const float2* __restrict__ slm,
    const unsigned short* __restrict__ row_idx, const int* __restrict__ row_cnt,
    const float* __restrict__ v, float* __restrict__ u)
{
  const int lane = threadIdx.x & 63;
  const int row  = blockIdx.x * 4 + (threadIdx.x >> 6);
  const int cnt  = row_cnt[row];
  if (cnt == 0) { if (lane == 0) u[row] = 1.0e9f; return; }
  const int b = row >> 12;
  const float2 a = tlm[row];
  const float2* __restrict__ sl = slm + (size_t)b * NN;
  const float*  __restrict__ vb = v + (size_t)b * NN;
  const unsigned short* __restrict__ lst = row_idx + (size_t)row * CAP;

  float t[CAP / 64];
  float mx = -3.0e38f;
#pragma unroll
  for (int i = 0; i < CAP / 64; ++i) {
    int j = i * 64 + lane;
    float tv = -3.0e38f;
    if (j < cnt) {
      int n = lst[j];
      float2 s = sl[n];
      float dx = a.x - s.x, dy = a.y - s.y;
      tv = (dx * dx + dy * dy) * kNegInvEps + vb[n];
    }
    t[i] = tv;
    mx = fmaxf(mx, tv);
  }
  mx = wave_reduce_max(mx);
  float ssum = 0.0f;
#pragma unroll
  for (int i = 0; i < CAP / 64; ++i) ssum += __expf(t[i] - mx);
  ssum = wave_reduce_sum(ssum);
  if (lane == 0) u[row] = -(mx + __logf(ssum));
}

// v[col] = !sv ? 0 : -lse(valid terms + cc copies of t=0)   (one wave per col)
__global__ __launch_bounds__(256) void lse_col_kernel(
    const float2* __restrict__ slm, const float2* __restrict__ tlm,
    const unsigned short* __restrict__ col_idx, const int* __restrict__ col_cnt,
    const int* __restrict__ smask, const int* __restrict__ ecnt,
    const float* __restrict__ u, float* __restrict__ v)
{
  const int lane = threadIdx.x & 63;
  const int col  = blockIdx.x * 4 + (threadIdx.x >> 6);
  if (!smask[col]) { if (lane == 0) v[col] = 0.0f; return; }
  const int cnt = col_cnt[col];
  const int b   = col >> 12;
  const int cc  = ecnt[b];
  if (cnt == 0 && cc == 0) { if (lane == 0) v[col] = 1.0e9f; return; }
  const float2 a = slm[col];
  const float2* __restrict__ tl = tlm + (size_t)b * MM;
  const float*  __restrict__ ub = u + (size_t)b * MM;
  const unsigned short* __restrict__ lst = col_idx + (size_t)col * CAP;

  float t[CAP / 64];
  float mx = -3.0e38f;
#pragma unroll
  for (int i = 0; i < CAP / 64; ++i) {
    int j = i * 64 + lane;
    float tv = -3.0e38f;
    if (j < cnt) {
      int m = lst[j];
      float2 s = tl[m];
      float dx = a.x - s.x, dy = a.y - s.y;
      tv = (dx * dx + dy * dy) * kNegInvEps + ub[m];
    }
    t[i] = tv;
    mx = fmaxf(mx, tv);
  }
  mx = wave_reduce_max(mx);
  if (cc > 0) mx = fmaxf(mx, 0.0f);   // contamination entries are t = 0.0 exactly
  float ssum = 0.0f;
#pragma unroll
  for (int i = 0; i < CAP / 64; ++i) ssum += __expf(t[i] - mx);
  ssum = wave_reduce_sum(ssum);
  if (lane == 0) v[col] = -(mx + __logf(ssum + (float)cc * __expf(0.0f - mx)));
}

// out[row,:] = sum_j attn_j * feats[n_j,:], one block per row, float4 gathers,
// 8 feat rows in flight across groups; inner loop unrolled x4 for load MLP.
__global__ __launch_bounds__(256) void output2_kernel(
    const float2* __restrict__ tlm, const float2* __restrict__ slm,
    const unsigned short* __restrict__ row_idx, const int* __restrict__ row_cnt,
    const float* __restrict__ u, const float* __restrict__ v,
    const float* __restrict__ feats, float* __restrict__ out)
{
  __shared__ float s_attn[CAP];
  __shared__ unsigned short s_id[CAP];
  __shared__ float4 s_red[256];

  const int row = blockIdx.x;
  const int tid = threadIdx.x;
  const int b   = row >> 12;
  const int cnt = row_cnt[row];
  float4* op = (float4*)(out + (size_t)row * CC);
  if (cnt == 0) {                      // covers !tgt_valid and !has_source
    if (tid < 32) op[tid] = make_float4(0.f, 0.f, 0.f, 0.f);
    return;
  }
  const float um = u[row];
  const float2 a = tlm[row];
  const float2* __restrict__ sl = slm + (size_t)b * NN;
  const float*  __restrict__ vb = v + (size_t)b * NN;
  const unsigned short* __restrict__ lst = row_idx + (size_t)row * CAP;

  for (int j = tid; j < cnt; j += 256) {
    int n = lst[j];
    float2 s = sl[n];
    float dx = a.x - s.x, dy = a.y - s.y;
    s_attn[j] = __expf((dx * dx + dy * dy) * kNegInvEps + um + vb[n]);
    s_id[j] = (unsigned short)n;
  }
  __syncthreads();

  const int g = tid >> 5, l = tid & 31;
  const float4* __restrict__ fb = (const float4*)(feats + (size_t)b * NN * CC);
  float4 acc = make_float4(0.f, 0.f, 0.f, 0.f);
  int j = g;
  // x4 unroll: 4 independent 512B gathers in flight per lane-group
  for (; j + 24 < cnt; j += 32) {
    float a0 = s_attn[j],      a1 = s_attn[j + 8];
    float a2 = s_attn[j + 16], a3 = s_attn[j + 24];
    int   n0 = s_id[j],        n1 = s_id[j + 8];
    int   n2 = s_id[j + 16],   n3 = s_id[j + 24];
    float4 f0 = fb[(size_t)n0 * 32 + l];
    float4 f1 = fb[(size_t)n1 * 32 + l];
    float4 f2 = fb[(size_t)n2 * 32 + l];
    float4 f3 = fb[(size_t)n3 * 32 + l];
    acc.x = fmaf(a0, f0.x, acc.x); acc.y = fmaf(a0, f0.y, acc.y);
    acc.z = fmaf(a0, f0.z, acc.z); acc.w = fmaf(a0, f0.w, acc.w);
    acc.x = fmaf(a1, f1.x, acc.x); acc.y = fmaf(a1, f1.y, acc.y);
    acc.z = fmaf(a1, f1.z, acc.z); acc.w = fmaf(a1, f1.w, acc.w);
    acc.x = fmaf(a2, f2.x, acc.x); acc.y = fmaf(a2, f2.y, acc.y);
    acc.z = fmaf(a2, f2.z, acc.z); acc.w = fmaf(a2, f2.w, acc.w);
    acc.x = fmaf(a3, f3.x, acc.x); acc.y = fmaf(a3, f3.y, acc.y);
    acc.z = fmaf(a3, f3.z, acc.z); acc.w = fmaf(a3, f3.w, acc.w);
  }
  for (; j < cnt; j += 8) {
    float aw = s_attn[j];
    int   n  = s_id[j];
    float4 f = fb[(size_t)n * 32 + l];
    acc.x = fmaf(aw, f.x, acc.x);
    acc.y = fmaf(aw, f.y, acc.y);
    acc.z = fmaf(aw, f.z, acc.z);
    acc.w = fmaf(aw, f.w, acc.w);
  }
  s_red[tid] = acc;
  __syncthreads();
  if (tid < 32) {
    float4 r = s_red[tid];
#pragma unroll
    for (int gg = 1; gg < 8; ++gg) {
      float4 p = s_red[gg * 32 + tid];
      r.x += p.x; r.y += p.y; r.z += p.z; r.w += p.w;
    }
    op[tid] = r;
  }
}

// ---------------------------------------------------------------------------
// FALLBACK: round-1 dense path (~128 KB workspace)
// ---------------------------------------------------------------------------

__global__ __launch_bounds__(256) void init_v_kernel(float* __restrict__ v) {
  int i = blockIdx.x * 256 + threadIdx.x;
  if (i < BB * NN) v[i] = 0.0f;
}

__global__ __launch_bounds__(256) void u_update_kernel(
    const float* __restrict__ src_locs, const float* __restrict__ tgt_locs,
    const int* __restrict__ src_valid, const int* __restrict__ tgt_valid,
    const float* __restrict__ v, float* __restrict__ u)
{
  const int lane = threadIdx.x & 63;
  const int row  = blockIdx.x * 4 + (threadIdx.x >> 6);
  const int b    = row / MM;
  const float tx = tgt_locs[row * 2 + 0];
  const float ty = tgt_locs[row * 2 + 1];
  const bool  tv = tgt_valid[row] != 0;
  const float2* __restrict__ sl  = (const float2*)(src_locs + (size_t)b * NN * 2);
  const float*  __restrict__ vb  = v + (size_t)b * NN;
  const int*    __restrict__ svb = src_valid + (size_t)b * NN;
  float mx = -3.0e38f;
#pragma unroll 4
  for (int i = 0; i < NN / 64; ++i) {
    int n = i * 64 + lane;
    float2 s = sl[n];
    float dx = tx - s.x, dy = ty - s.y;
    float d2 = dx * dx + dy * dy;
    bool valid = (d2 < kThresh2) & tv & (svb[n] != 0);
    float t = (valid ? d2 * kNegInvEps : kNegInf) + vb[n];
    mx = fmaxf(mx, t);
  }
  mx = wave_reduce_max(mx);
  float s = 0.0f;
#pragma unroll 4
  for (int i = 0; i < NN / 64; ++i) {
    int n = i * 64 + lane;
    float2 sc = sl[n];
    float dx = tx - sc.x, dy = ty - sc.y;
    float d2 = dx * dx + dy * dy;
    bool valid = (d2 < kThresh2) & tv & (svb[n] != 0);
    float t = (valid ? d2 * kNegInvEps : kNegInf) + vb[n];
    s += __expf(t - mx);
  }
  s = wave_reduce_sum(s);
  if (lane == 0) u[row] = -(mx + __logf(s));
}

__global__ __launch_bounds__(256) void v_update_kernel(
    const float* __restrict__ src_locs, const float* __restrict__ tgt_locs,
    const int* __restrict__ src_valid, const int* __restrict__ tgt_valid,
    const float* __restrict__ u, float* __restrict__ v)
{
  const int lane = threadIdx.x & 63;
  const int col  = blockIdx.x * 4 + (threadIdx.x >> 6);
  const int b    = col / NN;
  const float sx = src_locs[col * 2 + 0];
  const float sy = src_locs[col * 2 + 1];
  const bool  sv = src_valid[col] != 0;
  const float2* __restrict__ tl  = (const float2*)(tgt_locs + (size_t)b * MM * 2);
  const float*  __restrict__ ub  = u + (size_t)b * MM;
  const int*    __restrict__ tvb = tgt_valid + (size_t)b * MM;
  float mx = -3.0e38f;
#pragma unroll 4
  for (int i = 0; i < MM / 64; ++i) {
    int m = i * 64 + lane;
    float2 t2 = tl[m];
    float dx = t2.x - sx, dy = t2.y - sy;
    float d2 = dx * dx + dy * dy;
    bool valid = (d2 < kThresh2) & sv & (tvb[m] != 0);
    float t = (valid ? d2 * kNegInvEps : kNegInf) + ub[m];
    mx = fmaxf(mx, t);
  }
  mx = wave_reduce_max(mx);
  float s = 0.0f;
#pragma unroll 4
  for (int i = 0; i < MM / 64; ++i) {
    int m = i * 64 + lane;
    float2 t2 = tl[m];
    float dx = t2.x - sx, dy = t2.y - sy;
    float d2 = dx * dx + dy * dy;
    bool valid = (d2 < kThresh2) & sv & (tvb[m] != 0);
    float t = (valid ? d2 * kNegInvEps : kNegInf) + ub[m];
    s += __expf(t - mx);
  }
  s = wave_reduce_sum(s);
  if (lane == 0) v[col] = sv ? -(mx + __logf(s)) : 0.0f;
}

__global__ __launch_bounds__(256) void output_kernel(
    const float* __restrict__ src_locs, const float* __restrict__ tgt_locs,
    const int* __restrict__ src_valid, const int* __restrict__ tgt_valid,
    const float* __restrict__ u, const float* __restrict__ v,
    const float* __restrict__ feats, float* __restrict__ out)
{
  __shared__ float s_attn[NN];
  __shared__ int   s_idx[NN];
  __shared__ int   s_cnt;
  __shared__ float s_part[CC];
  const int row = blockIdx.x;
  const int b   = row / MM;
  const int tid = threadIdx.x;
  if (tid == 0) s_cnt = 0;
  __syncthreads();
  const float tx = tgt_locs[row * 2 + 0];
  const float ty = tgt_locs[row * 2 + 1];
  const bool  tv = tgt_valid[row] != 0;
  const float um = u[row];
  const float2* __restrict__ sl  = (const float2*)(src_locs + (size_t)b * NN * 2);
  const float*  __restrict__ vb  = v + (size_t)b * NN;
  const int*    __restrict__ svb = src_valid + (size_t)b * NN;
#pragma unroll 4
  for (int i = 0; i < NN / 256; ++i) {
    int n = i * 256 + tid;
    float2 s = sl[n];
    float dx = tx - s.x, dy = ty - s.y;
    float d2 = dx * dx + dy * dy;
    bool valid = (d2 < kThresh2) & tv & (svb[n] != 0);
    if (valid) {
      float a = __expf((d2 * kNegInvEps + um) + vb[n]);
      int p = atomicAdd(&s_cnt, 1);
      s_attn[p] = a;
      s_idx[p]  = n;
    }
  }
  __syncthreads();
  const int cnt = s_cnt;
  const int g = tid >> 7;
  const int c = tid & (CC - 1);
  const float* __restrict__ fb = feats + (size_t)b * NN * CC;
  float acc = 0.0f;
  for (int j = g; j < cnt; j += 2) {
    float a = s_attn[j];
    int   n = s_idx[j];
    acc = fmaf(a, fb[(size_t)n * CC + c], acc);
  }
  if (g == 1) s_part[c] = acc;
  __syncthreads();
  if (g == 0) {
    float r = (cnt > 0) ? (acc + s_part[c]) : 0.0f;
    out[(size_t)row * CC + c] = r;
  }
}

// ---------------------------------------------------------------------------

extern "C" void kernel_launch(void* const* d_in, const int* in_sizes, int n_in,
                              void* d_out, int out_size, void* d_ws, size_t ws_size,
                              hipStream_t stream) {
  const float* feats = (const float*)d_in[0];
  const float* sloc  = (const float*)d_in[1];
  const float* tloc  = (const float*)d_in[2];
  const int*   smask = (const int*)d_in[3];
  const int*   tmask = (const int*)d_in[4];
  float* out = (float*)d_out;

  // workspace layout (fast path)
  char* p = (char*)d_ws;
  float* u_   = (float*)p;            p += (size_t)BB * MM * 4;
  float* v_   = (float*)p;            p += (size_t)BB * NN * 4;
  int* row_cnt = (int*)p;             p += (size_t)BB * MM * 4;
  int* col_cnt = (int*)p;             p += (size_t)BB * NN * 4;
  int* ecnt    = (int*)p;             p += 256;
  float2* slm  = (float2*)p;          p += (size_t)BB * NN * 8;
  float2* tlm  = (float2*)p;          p += (size_t)BB * MM * 8;
  unsigned short* row_idx = (unsigned short*)p; p += (size_t)BB * MM * CAP * 2;
  unsigned short* col_idx = (unsigned short*)p; p += (size_t)BB * NN * CAP * 2;
  int* bin_start = (int*)p;           p += (size_t)8 * CSTRIDE * 4;
  float2* bin_loc = (float2*)p;       p += (size_t)8 * 4096 * 8;
  unsigned short* bin_pid = (unsigned short*)p; p += (size_t)8 * 4096 * 2;
  size_t required = (size_t)(p - (char*)d_ws);

  if (ws_size >= required) {
    prep_bins_kernel<<<72, 256, 0, stream>>>(
        sloc, tloc, smask, tmask, v_, ecnt, slm, tlm,
        bin_start, bin_loc, bin_pid);
    sweep5_kernel<<<2 * BB * MM / 4, 256, 0, stream>>>(
        slm, tlm, bin_start, bin_loc, bin_pid,
        row_idx, row_cnt, col_idx, col_cnt, ecnt);
    for (int it = 0; it < 3; ++it) {
      lse_row_kernel<<<BB * MM / 4, 256, 0, stream>>>(tlm, slm, row_idx, row_cnt, v_, u_);
      lse_col_kernel<<<BB * NN / 4, 256, 0, stream>>>(slm, tlm, col_idx, col_cnt,
                                                      smask, ecnt, u_, v_);
    }
    output2_kernel<<<BB * MM, 256, 0, stream>>>(tlm, slm, row_idx, row_cnt,
                                                u_, v_, feats, out);
  } else {
    // minimal-workspace fallback: round-1 dense path
    float* u = (float*)d_ws;
    float* v = u + (size_t)BB * MM;
    init_v_kernel<<<(BB * NN + 255) / 256, 256, 0, stream>>>(v);
    for (int it = 0; it < 3; ++it) {
      u_update_kernel<<<BB * MM / 4, 256, 0, stream>>>(sloc, tloc, smask, tmask, v, u);
      v_update_kernel<<<BB * NN / 4, 256, 0, stream>>>(sloc, tloc, smask, tmask, u, v);
    }
    output_kernel<<<BB * MM, 256, 0, stream>>>(sloc, tloc, smask, tmask, u, v, feats, out);
  }
}